// Round 1
// baseline (63027.264 us; speedup 1.0000x reference)
//
#include <hip/hip_runtime.h>
#include <math.h>

#define B_    128
#define T_    256
#define DIM_  512
#define HID_  1024
#define OUT_  512
#define TAG_  64
#define K3_   3072   // 3*HID
#define KA_   2048   // OUT(x_tm1) + DIM(inp) + HID(s)

__device__ __forceinline__ float hardsig(float x){
    return fminf(fmaxf(0.2f*x + 0.5f, 0.f), 1.f);
}

// -------- init: xbuf <- x0, sbuf0 <- s0 --------
__global__ void k_init(const float* __restrict__ x0, const float* __restrict__ s0,
                       float* __restrict__ xbuf, float* __restrict__ sbuf){
    int i = blockIdx.x*256 + threadIdx.x;
    if (i < B_*OUT_) xbuf[i] = x0[i];
    if (i < B_*HID_) sbuf[i] = s0[i];
}

// -------- phase A: pre[128x3072] = [x_tm1, inp_t, s_tm1] @ [W; V; U(rz only)] + b --------
// grid (4, 48), block 256. BM=32, BN=64, TK=16, micro 2x4.
__global__ __launch_bounds__(256) void k_preA(
    const float* __restrict__ xbuf, const float* __restrict__ xin,
    const float* __restrict__ sprev,
    const float* __restrict__ W, const float* __restrict__ Vr,
    const float* __restrict__ Vz, const float* __restrict__ Vs,
    const float* __restrict__ U, const float* __restrict__ bias,
    float* __restrict__ pre, int t)
{
    __shared__ float As[16][33];
    __shared__ float Bs[16][68];
    const int tid    = threadIdx.x;
    const int m_base = blockIdx.x * 32;
    const int n_base = blockIdx.y * 64;
    const int nseg   = n_base >> 10;        // 0=r cols, 1=z cols, 2=s cols
    const int m0  = (tid >> 4) * 2;
    const int n0  = (tid & 15) * 4;
    const int lrA = tid >> 4;               // 0..15
    const int lkA = tid & 15;               // 0..15
    const int lkB = tid >> 4;               // 0..15
    const int lnB = (tid & 15) * 4;
    const int nc  = n_base + lnB;           // global output col for B loads
    float acc[2][4] = {{0.f,0.f,0.f,0.f},{0.f,0.f,0.f,0.f}};
    const int kmax = (nseg == 2) ? 1024 : KA_;   // s-cols get no U contribution

    for (int kb = 0; kb < kmax; kb += 16){
        // ---- stage A operand (activations) ----
        int k = kb + lkA;
        int r0 = m_base + lrA, r1 = r0 + 16;
        float a0, a1;
        if (k < 512){
            a0 = xbuf[r0*OUT_ + k];
            a1 = xbuf[r1*OUT_ + k];
        } else if (k < 1024){
            int kk2 = k - 512;
            a0 = xin[r0*(T_*DIM_) + t*DIM_ + kk2];
            a1 = xin[r1*(T_*DIM_) + t*DIM_ + kk2];
        } else {
            int kk2 = k - 1024;
            a0 = sprev[r0*HID_ + kk2];
            a1 = sprev[r1*HID_ + kk2];
        }
        As[lkA][lrA]      = a0;
        As[lkA][lrA + 16] = a1;
        // ---- stage B operand (weights, region-dispatched) ----
        int kB = kb + lkB;
        const float* p;
        if (kB < 512){
            p = W + kB*K3_ + nc;
        } else if (kB < 1024){
            const float* V = (nseg==0) ? Vr : ((nseg==1) ? Vz : Vs);
            p = V + (kB-512)*HID_ + (nc - (nseg<<10));
        } else {
            p = U + (kB-1024)*K3_ + nc;     // only reached when nseg<2
        }
        Bs[lkB][lnB+0]=p[0]; Bs[lkB][lnB+1]=p[1]; Bs[lkB][lnB+2]=p[2]; Bs[lkB][lnB+3]=p[3];
        __syncthreads();
        #pragma unroll
        for (int kk = 0; kk < 16; ++kk){
            float av0 = As[kk][m0], av1 = As[kk][m0+1];
            float b0 = Bs[kk][n0], b1 = Bs[kk][n0+1], b2 = Bs[kk][n0+2], b3 = Bs[kk][n0+3];
            acc[0][0] += av0*b0; acc[0][1] += av0*b1; acc[0][2] += av0*b2; acc[0][3] += av0*b3;
            acc[1][0] += av1*b0; acc[1][1] += av1*b1; acc[1][2] += av1*b2; acc[1][3] += av1*b3;
        }
        __syncthreads();
    }
    #pragma unroll
    for (int i = 0; i < 2; ++i){
        int rr = m_base + m0 + i;
        #pragma unroll
        for (int j = 0; j < 4; ++j){
            int cc = n_base + n0 + j;
            pre[rr*K3_ + cc] = acc[i][j] + bias[cc];
        }
    }
}

// -------- phase B: s_next = (1-z)*s + z*tanh(pre_s + (r*s)@U_s) --------
// grid (4, 16), block 256. BM=32, BN=64, K=1024.
__global__ __launch_bounds__(256) void k_supd(
    const float* __restrict__ pre, const float* __restrict__ sprev,
    const float* __restrict__ U, float* __restrict__ snext)
{
    __shared__ float As[16][33];
    __shared__ float Bs[16][68];
    const int tid    = threadIdx.x;
    const int m_base = blockIdx.x * 32;
    const int n_base = blockIdx.y * 64;
    const int m0  = (tid >> 4) * 2;
    const int n0  = (tid & 15) * 4;
    const int lrA = tid >> 4;
    const int lkA = tid & 15;
    const int lkB = tid >> 4;
    const int lnB = (tid & 15) * 4;
    float acc[2][4] = {{0.f,0.f,0.f,0.f},{0.f,0.f,0.f,0.f}};

    for (int kb = 0; kb < HID_; kb += 16){
        int k = kb + lkA;
        int r0 = m_base + lrA, r1 = r0 + 16;
        As[lkA][lrA]      = hardsig(pre[r0*K3_ + k]) * sprev[r0*HID_ + k];
        As[lkA][lrA + 16] = hardsig(pre[r1*K3_ + k]) * sprev[r1*HID_ + k];
        const float* p = U + (kb+lkB)*K3_ + 2048 + n_base + lnB;
        Bs[lkB][lnB+0]=p[0]; Bs[lkB][lnB+1]=p[1]; Bs[lkB][lnB+2]=p[2]; Bs[lkB][lnB+3]=p[3];
        __syncthreads();
        #pragma unroll
        for (int kk = 0; kk < 16; ++kk){
            float av0 = As[kk][m0], av1 = As[kk][m0+1];
            float b0 = Bs[kk][n0], b1 = Bs[kk][n0+1], b2 = Bs[kk][n0+2], b3 = Bs[kk][n0+3];
            acc[0][0] += av0*b0; acc[0][1] += av0*b1; acc[0][2] += av0*b2; acc[0][3] += av0*b3;
            acc[1][0] += av1*b0; acc[1][1] += av1*b1; acc[1][2] += av1*b2; acc[1][3] += av1*b3;
        }
        __syncthreads();
    }
    #pragma unroll
    for (int i = 0; i < 2; ++i){
        int rr = m_base + m0 + i;
        #pragma unroll
        for (int j = 0; j < 4; ++j){
            int cc = n_base + n0 + j;
            float z    = hardsig(pre[rr*K3_ + 1024 + cc]);
            float xs   = pre[rr*K3_ + 2048 + cc];
            float sold = sprev[rr*HID_ + cc];
            float s1   = tanhf(xs + acc[i][j]);
            snext[rr*HID_ + cc] = (1.f - z)*sold + z*s1;
        }
    }
}

// -------- phase C: logits[128x512] = s_t @ W_x + b_x --------
// grid (4, 8), block 256. BM=32, BN=64, K=1024.
__global__ __launch_bounds__(256) void k_logits(
    const float* __restrict__ st, const float* __restrict__ Wx,
    const float* __restrict__ bx, float* __restrict__ logits)
{
    __shared__ float As[16][33];
    __shared__ float Bs[16][68];
    const int tid    = threadIdx.x;
    const int m_base = blockIdx.x * 32;
    const int n_base = blockIdx.y * 64;
    const int m0  = (tid >> 4) * 2;
    const int n0  = (tid & 15) * 4;
    const int lrA = tid >> 4;
    const int lkA = tid & 15;
    const int lkB = tid >> 4;
    const int lnB = (tid & 15) * 4;
    float acc[2][4] = {{0.f,0.f,0.f,0.f},{0.f,0.f,0.f,0.f}};

    for (int kb = 0; kb < HID_; kb += 16){
        int k = kb + lkA;
        int r0 = m_base + lrA, r1 = r0 + 16;
        As[lkA][lrA]      = st[r0*HID_ + k];
        As[lkA][lrA + 16] = st[r1*HID_ + k];
        const float* p = Wx + (kb+lkB)*OUT_ + n_base + lnB;
        Bs[lkB][lnB+0]=p[0]; Bs[lkB][lnB+1]=p[1]; Bs[lkB][lnB+2]=p[2]; Bs[lkB][lnB+3]=p[3];
        __syncthreads();
        #pragma unroll
        for (int kk = 0; kk < 16; ++kk){
            float av0 = As[kk][m0], av1 = As[kk][m0+1];
            float b0 = Bs[kk][n0], b1 = Bs[kk][n0+1], b2 = Bs[kk][n0+2], b3 = Bs[kk][n0+3];
            acc[0][0] += av0*b0; acc[0][1] += av0*b1; acc[0][2] += av0*b2; acc[0][3] += av0*b3;
            acc[1][0] += av1*b0; acc[1][1] += av1*b1; acc[1][2] += av1*b2; acc[1][3] += av1*b3;
        }
        __syncthreads();
    }
    #pragma unroll
    for (int i = 0; i < 2; ++i){
        int rr = m_base + m0 + i;
        #pragma unroll
        for (int j = 0; j < 4; ++j){
            int cc = n_base + n0 + j;
            logits[rr*OUT_ + cc] = acc[i][j] + bx[cc];
        }
    }
}

// -------- phase D: x_t = softmax(logits); out[:,t,:] = softmax(x_t @ W_y + b_y) --------
// grid 128 (one row each), block 256.
__global__ __launch_bounds__(256) void k_soft(
    const float* __restrict__ logits, const float* __restrict__ Wy,
    const float* __restrict__ by, float* __restrict__ xbuf,
    float* __restrict__ out, int t)
{
    __shared__ float xs[512];
    __shared__ float red[256];
    const int r = blockIdx.x, tid = threadIdx.x;
    float v0 = logits[r*OUT_ + tid];
    float v1 = logits[r*OUT_ + 256 + tid];
    // --- row max ---
    red[tid] = fmaxf(v0, v1);
    __syncthreads();
    for (int s = 128; s > 0; s >>= 1){
        if (tid < s) red[tid] = fmaxf(red[tid], red[tid+s]);
        __syncthreads();
    }
    float mx = red[0];
    __syncthreads();
    // --- exp + sum ---
    float e0 = expf(v0 - mx), e1 = expf(v1 - mx);
    red[tid] = e0 + e1;
    __syncthreads();
    for (int s = 128; s > 0; s >>= 1){
        if (tid < s) red[tid] += red[tid+s];
        __syncthreads();
    }
    float inv = 1.f / red[0];
    __syncthreads();
    float x0v = e0*inv, x1v = e1*inv;
    xs[tid]       = x0v;
    xs[tid + 256] = x1v;
    xbuf[r*OUT_ + tid]       = x0v;
    xbuf[r*OUT_ + 256 + tid] = x1v;
    __syncthreads();
    // --- t-logits: 64 outputs, 4 partial threads each ---
    const int j = tid & 63, part = tid >> 6;
    float p = 0.f;
    const int k0 = part * 128;
    #pragma unroll 4
    for (int k = k0; k < k0 + 128; ++k) p += xs[k] * Wy[k*TAG_ + j];
    red[tid] = p;    // red[part*64 + j] == red[tid]
    __syncthreads();
    if (tid < 64){
        float tl = red[tid] + red[tid+64] + red[tid+128] + red[tid+192] + by[tid];
        float wm = tl;
        #pragma unroll
        for (int off = 32; off > 0; off >>= 1) wm = fmaxf(wm, __shfl_xor(wm, off));
        float ex = expf(tl - wm);
        float sm = ex;
        #pragma unroll
        for (int off = 32; off > 0; off >>= 1) sm += __shfl_xor(sm, off);
        out[((long)r*T_ + t)*TAG_ + tid] = ex / sm;
    }
}

extern "C" void kernel_launch(void* const* d_in, const int* in_sizes, int n_in,
                              void* d_out, int out_size, void* d_ws, size_t ws_size,
                              hipStream_t stream){
    const float* x   = (const float*)d_in[0];
    const float* x0  = (const float*)d_in[1];
    const float* s0  = (const float*)d_in[2];
    const float* W   = (const float*)d_in[3];
    const float* U   = (const float*)d_in[4];
    const float* b   = (const float*)d_in[5];
    const float* Wx  = (const float*)d_in[6];
    const float* bx  = (const float*)d_in[7];
    const float* Vr  = (const float*)d_in[8];
    const float* Vz  = (const float*)d_in[9];
    const float* Vs  = (const float*)d_in[10];
    const float* Wy  = (const float*)d_in[11];
    const float* by  = (const float*)d_in[12];
    float* out = (float*)d_out;

    float* ws     = (float*)d_ws;
    float* xbuf   = ws;                    // 128*512
    float* sb0    = xbuf + B_*OUT_;        // 128*1024
    float* sb1    = sb0  + B_*HID_;        // 128*1024
    float* pre    = sb1  + B_*HID_;        // 128*3072
    float* logits = pre  + B_*K3_;         // 128*512

    k_init<<<512, 256, 0, stream>>>(x0, s0, xbuf, sb0);
    for (int t = 0; t < T_; ++t){
        float* sp = (t & 1) ? sb1 : sb0;
        float* sn = (t & 1) ? sb0 : sb1;
        k_preA  <<<dim3(4,48), 256, 0, stream>>>(xbuf, x, sp, W, Vr, Vz, Vs, U, b, pre, t);
        k_supd  <<<dim3(4,16), 256, 0, stream>>>(pre, sp, U, sn);
        k_logits<<<dim3(4, 8), 256, 0, stream>>>(sn, Wx, bx, logits);
        k_soft  <<<128,        256, 0, stream>>>(logits, Wy, by, xbuf, out, t);
    }
}

// Round 2
// 17240.326 us; speedup vs baseline: 3.6558x; 3.6558x over previous
//
#include <hip/hip_runtime.h>
#include <math.h>

#define B_    128
#define T_    256
#define DIM_  512
#define HID_  1024
#define OUT_  512
#define TAG_  64
#define K3_   3072

typedef float f32x4 __attribute__((ext_vector_type(4)));
typedef short bf16x8 __attribute__((ext_vector_type(8)));

#define MFMA(a,b,c) __builtin_amdgcn_mfma_f32_16x16x32_bf16(a,b,c,0,0,0)

__device__ __forceinline__ unsigned short f2b(float f){
    unsigned int u = __float_as_uint(f);
    u = (u + 0x7fffu + ((u >> 16) & 1u)) >> 16;   // RNE
    return (unsigned short)u;
}
__device__ __forceinline__ float hardsig(float x){
    return fminf(fmaxf(0.2f*x + 0.5f, 0.f), 1.f);
}
__device__ __forceinline__ bf16x8 ld8(const unsigned short* p){
    return *(const bf16x8*)p;
}
__device__ __forceinline__ bf16x8 ld8f(const float* p){
    float4 a = *(const float4*)p;
    float4 b = *(const float4*)(p + 4);
    bf16x8 r;
    r[0]=(short)f2b(a.x); r[1]=(short)f2b(a.y); r[2]=(short)f2b(a.z); r[3]=(short)f2b(a.w);
    r[4]=(short)f2b(b.x); r[5]=(short)f2b(b.y); r[6]=(short)f2b(b.z); r[7]=(short)f2b(b.w);
    return r;
}

// ---------- prep: transpose+convert weights fp32 [K][N-slice] -> bf16 [N][K] ----------
// dst[n*K + k] = bf16(src[k*ld + col_off + n]); grid (K/32, N/32), block 256.
__global__ __launch_bounds__(256) void k_tr(
    unsigned short* __restrict__ dst, const float* __restrict__ src,
    int K, int ld, int col_off)
{
    __shared__ float tile[32][33];
    const int kb = blockIdx.x * 32, nb = blockIdx.y * 32;
    const int tx = threadIdx.x & 31, ty = threadIdx.x >> 5;  // ty 0..7
    #pragma unroll
    for (int i = 0; i < 4; ++i){
        int kl = ty + i*8;
        tile[kl][tx] = src[(size_t)(kb + kl)*ld + col_off + nb + tx];
    }
    __syncthreads();
    #pragma unroll
    for (int i = 0; i < 4; ++i){
        int nl = ty + i*8;
        dst[(size_t)(nb + nl)*K + kb + tx] = f2b(tile[tx][nl]);
    }
}

// ---------- prep: convert x to bf16 (vectorized) ----------
__global__ __launch_bounds__(256) void k_cvtx(
    const float4* __restrict__ src, ushort4* __restrict__ dst, int n4)
{
    int i = blockIdx.x * 256 + threadIdx.x;
    if (i < n4){
        float4 v = src[i];
        ushort4 o;
        o.x = f2b(v.x); o.y = f2b(v.y); o.z = f2b(v.z); o.w = f2b(v.w);
        dst[i] = o;
    }
}

// ---------- init: xbuf_b <- bf16(x0); sb0 <- s0; s_b <- bf16(s0) ----------
__global__ __launch_bounds__(256) void k_init(
    const float* __restrict__ x0, const float* __restrict__ s0,
    unsigned short* __restrict__ xbuf_b, float* __restrict__ sb0,
    unsigned short* __restrict__ s_b)
{
    int i = blockIdx.x * 256 + threadIdx.x;
    if (i < B_*OUT_) xbuf_b[i] = f2b(x0[i]);
    if (i < B_*HID_){ sb0[i] = s0[i]; s_b[i] = f2b(s0[i]); }
}

// ---------- phase A: pre = [x_tm1|inp_t|s_tm1] @ [W;V;U_rz] + b ----------
// 768 waves: mt = wid&7 (M/16), nt = wid>>3 (96 n-tiles of 32). 192 blocks x 256.
// r-columns (nseg==0) are fused to rs_b = bf16(hardsig(pre_r) * s); z/xs go to pre fp32.
__global__ __launch_bounds__(256) void k_gemmA(
    const unsigned short* __restrict__ xbuf_b,
    const unsigned short* __restrict__ xb16,
    const float* __restrict__ xf,
    const unsigned short* __restrict__ s_b,
    const float* __restrict__ sp,
    const unsigned short* __restrict__ Wt,
    const unsigned short* __restrict__ Vrt,
    const unsigned short* __restrict__ Vzt,
    const unsigned short* __restrict__ Vst,
    const unsigned short* __restrict__ Urzt,
    const float* __restrict__ bias,
    float* __restrict__ pre,
    unsigned short* __restrict__ rs_b,
    int t, int use_xb)
{
    const int wid  = (blockIdx.x * 256 + threadIdx.x) >> 6;   // 0..767
    const int lane = threadIdx.x & 63;
    const int mt   = wid & 7;
    const int nt   = wid >> 3;        // 0..95
    const int n0   = nt * 32;
    const int nseg = n0 >> 10;        // 0=r, 1=z, 2=s
    const int l15  = lane & 15;
    const int kch  = lane >> 4;       // K-octet select
    const int arow = mt*16 + l15;     // A-operand row for this lane
    f32x4 acc0 = {0.f,0.f,0.f,0.f};
    f32x4 acc1 = {0.f,0.f,0.f,0.f};

    // seg0: x_tm1 @ W   (K = 512)
    {
        const unsigned short* ab = xbuf_b + arow*OUT_ + kch*8;
        const unsigned short* b0 = Wt + (size_t)(n0 + l15)*OUT_ + kch*8;
        const unsigned short* b1 = b0 + 16*OUT_;
        #pragma unroll 4
        for (int kb = 0; kb < OUT_; kb += 32){
            bf16x8 a = ld8(ab + kb);
            acc0 = MFMA(a, ld8(b0 + kb), acc0);
            acc1 = MFMA(a, ld8(b1 + kb), acc1);
        }
    }
    // seg1: inp_t @ V   (K = 512)
    {
        const unsigned short* Vt = (nseg==0) ? Vrt : ((nseg==1) ? Vzt : Vst);
        const int nl = n0 - (nseg << 10);
        const unsigned short* b0 = Vt + (size_t)(nl + l15)*DIM_ + kch*8;
        const unsigned short* b1 = b0 + 16*DIM_;
        if (use_xb){
            const unsigned short* ab = xb16 + ((size_t)arow*T_ + t)*DIM_ + kch*8;
            #pragma unroll 4
            for (int kb = 0; kb < DIM_; kb += 32){
                bf16x8 a = ld8(ab + kb);
                acc0 = MFMA(a, ld8(b0 + kb), acc0);
                acc1 = MFMA(a, ld8(b1 + kb), acc1);
            }
        } else {
            const float* af = xf + ((size_t)arow*T_ + t)*DIM_ + kch*8;
            #pragma unroll 2
            for (int kb = 0; kb < DIM_; kb += 32){
                bf16x8 a = ld8f(af + kb);
                acc0 = MFMA(a, ld8(b0 + kb), acc0);
                acc1 = MFMA(a, ld8(b1 + kb), acc1);
            }
        }
    }
    // seg2: s_tm1 @ U_rz  (K = 1024, only r/z columns)
    if (nseg < 2){
        const unsigned short* ab = s_b + arow*HID_ + kch*8;
        const unsigned short* b0 = Urzt + (size_t)(n0 + l15)*HID_ + kch*8;
        const unsigned short* b1 = b0 + 16*HID_;
        #pragma unroll 4
        for (int kb = 0; kb < HID_; kb += 32){
            bf16x8 a = ld8(ab + kb);
            acc0 = MFMA(a, ld8(b0 + kb), acc0);
            acc1 = MFMA(a, ld8(b1 + kb), acc1);
        }
    }
    // epilogue: C row = mt*16 + (lane>>4)*4 + q, col = n0 + half*16 + (lane&15)
    const int rbase = mt*16 + kch*4;
    #pragma unroll
    for (int half = 0; half < 2; ++half){
        f32x4 acc = half ? acc1 : acc0;
        const int col = n0 + half*16 + l15;
        const float bv = bias[col];
        #pragma unroll
        for (int q = 0; q < 4; ++q){
            const int r = rbase + q;
            const float v = acc[q] + bv;
            if (nseg == 0){
                float rs = hardsig(v) * sp[r*HID_ + col];
                rs_b[r*HID_ + col] = f2b(rs);
            } else {
                pre[(size_t)r*K3_ + col] = v;
            }
        }
    }
}

// ---------- phase B: s_next = (1-z)*s + z*tanh(xs + rs @ U_s) ----------
// 256 waves -> 64 blocks.
__global__ __launch_bounds__(256) void k_gemmB(
    const unsigned short* __restrict__ rs_b,
    const unsigned short* __restrict__ Ust,
    const float* __restrict__ pre,
    const float* __restrict__ sp,
    float* __restrict__ snf,
    unsigned short* __restrict__ s_b)
{
    const int wid  = (blockIdx.x * 256 + threadIdx.x) >> 6;   // 0..255
    const int lane = threadIdx.x & 63;
    const int mt = wid & 7;
    const int nt = wid >> 3;      // 0..31
    const int n0 = nt * 32;
    const int l15 = lane & 15;
    const int kch = lane >> 4;
    const int arow = mt*16 + l15;
    f32x4 acc0 = {0.f,0.f,0.f,0.f};
    f32x4 acc1 = {0.f,0.f,0.f,0.f};
    const unsigned short* ab = rs_b + arow*HID_ + kch*8;
    const unsigned short* b0 = Ust + (size_t)(n0 + l15)*HID_ + kch*8;
    const unsigned short* b1 = b0 + 16*HID_;
    #pragma unroll 4
    for (int kb = 0; kb < HID_; kb += 32){
        bf16x8 a = ld8(ab + kb);
        acc0 = MFMA(a, ld8(b0 + kb), acc0);
        acc1 = MFMA(a, ld8(b1 + kb), acc1);
    }
    const int rbase = mt*16 + kch*4;
    #pragma unroll
    for (int half = 0; half < 2; ++half){
        f32x4 acc = half ? acc1 : acc0;
        const int col = n0 + half*16 + l15;
        #pragma unroll
        for (int q = 0; q < 4; ++q){
            const int r = rbase + q;
            float z  = hardsig(pre[(size_t)r*K3_ + HID_ + col]);
            float xs = pre[(size_t)r*K3_ + 2*HID_ + col];
            float so = sp[r*HID_ + col];
            float s1 = tanhf(xs + acc[q]);
            float sn = (1.f - z)*so + z*s1;
            snf[r*HID_ + col] = sn;
            s_b[r*HID_ + col] = f2b(sn);
        }
    }
}

// ---------- phase C: logits = s_t @ W_x + b_x ---------- 128 waves -> 32 blocks.
__global__ __launch_bounds__(256) void k_gemmC(
    const unsigned short* __restrict__ s_b,
    const unsigned short* __restrict__ Wxt,
    const float* __restrict__ bx,
    float* __restrict__ logits)
{
    const int wid  = (blockIdx.x * 256 + threadIdx.x) >> 6;   // 0..127
    const int lane = threadIdx.x & 63;
    const int mt = wid & 7;
    const int nt = wid >> 3;      // 0..15
    const int n0 = nt * 32;
    const int l15 = lane & 15;
    const int kch = lane >> 4;
    const int arow = mt*16 + l15;
    f32x4 acc0 = {0.f,0.f,0.f,0.f};
    f32x4 acc1 = {0.f,0.f,0.f,0.f};
    const unsigned short* ab = s_b + arow*HID_ + kch*8;
    const unsigned short* b0 = Wxt + (size_t)(n0 + l15)*HID_ + kch*8;
    const unsigned short* b1 = b0 + 16*HID_;
    #pragma unroll 4
    for (int kb = 0; kb < HID_; kb += 32){
        bf16x8 a = ld8(ab + kb);
        acc0 = MFMA(a, ld8(b0 + kb), acc0);
        acc1 = MFMA(a, ld8(b1 + kb), acc1);
    }
    const int rbase = mt*16 + kch*4;
    #pragma unroll
    for (int half = 0; half < 2; ++half){
        f32x4 acc = half ? acc1 : acc0;
        const int col = n0 + half*16 + l15;
        #pragma unroll
        for (int q = 0; q < 4; ++q){
            logits[(rbase + q)*OUT_ + col] = acc[q] + bx[col];
        }
    }
}

// ---------- phase D: x_t = softmax(logits); out[:,t,:] = softmax(x_t @ W_y + b_y) ----------
__global__ __launch_bounds__(256) void k_soft(
    const float* __restrict__ logits, const float* __restrict__ Wy,
    const float* __restrict__ by, unsigned short* __restrict__ xbuf_b,
    float* __restrict__ out, int t)
{
    __shared__ float xs[512];
    __shared__ float red[256];
    const int r = blockIdx.x, tid = threadIdx.x;
    float v0 = logits[r*OUT_ + tid];
    float v1 = logits[r*OUT_ + 256 + tid];
    red[tid] = fmaxf(v0, v1);
    __syncthreads();
    for (int s = 128; s > 0; s >>= 1){
        if (tid < s) red[tid] = fmaxf(red[tid], red[tid+s]);
        __syncthreads();
    }
    float mx = red[0];
    __syncthreads();
    float e0 = expf(v0 - mx), e1 = expf(v1 - mx);
    red[tid] = e0 + e1;
    __syncthreads();
    for (int s = 128; s > 0; s >>= 1){
        if (tid < s) red[tid] += red[tid+s];
        __syncthreads();
    }
    float inv = 1.f / red[0];
    __syncthreads();
    float x0v = e0*inv, x1v = e1*inv;
    xs[tid]       = x0v;
    xs[tid + 256] = x1v;
    xbuf_b[r*OUT_ + tid]       = f2b(x0v);
    xbuf_b[r*OUT_ + 256 + tid] = f2b(x1v);
    __syncthreads();
    const int j = tid & 63, part = tid >> 6;
    float p = 0.f;
    const int k0 = part * 128;
    #pragma unroll 4
    for (int k = k0; k < k0 + 128; ++k) p += xs[k] * Wy[k*TAG_ + j];
    red[tid] = p;
    __syncthreads();
    if (tid < 64){
        float tl = red[tid] + red[tid+64] + red[tid+128] + red[tid+192] + by[tid];
        float wm = tl;
        #pragma unroll
        for (int off = 32; off > 0; off >>= 1) wm = fmaxf(wm, __shfl_xor(wm, off));
        float ex = expf(tl - wm);
        float sm = ex;
        #pragma unroll
        for (int off = 32; off > 0; off >>= 1) sm += __shfl_xor(sm, off);
        out[((long)r*T_ + t)*TAG_ + tid] = ex / sm;
    }
}

extern "C" void kernel_launch(void* const* d_in, const int* in_sizes, int n_in,
                              void* d_out, int out_size, void* d_ws, size_t ws_size,
                              hipStream_t stream){
    const float* x   = (const float*)d_in[0];
    const float* x0  = (const float*)d_in[1];
    const float* s0  = (const float*)d_in[2];
    const float* W   = (const float*)d_in[3];
    const float* U   = (const float*)d_in[4];
    const float* b   = (const float*)d_in[5];
    const float* Wx  = (const float*)d_in[6];
    const float* bx  = (const float*)d_in[7];
    const float* Vr  = (const float*)d_in[8];
    const float* Vz  = (const float*)d_in[9];
    const float* Vs  = (const float*)d_in[10];
    const float* Wy  = (const float*)d_in[11];
    const float* by  = (const float*)d_in[12];
    float* out = (float*)d_out;

    char* ws = (char*)d_ws;
    size_t off = 0;
    auto alloc = [&](size_t bytes) -> size_t {
        size_t o = off; off = (off + bytes + 255) & ~(size_t)255; return o;
    };
    unsigned short* Wt     = (unsigned short*)(ws + alloc((size_t)K3_*OUT_*2));
    unsigned short* Urzt   = (unsigned short*)(ws + alloc((size_t)2048*HID_*2));
    unsigned short* Ust    = (unsigned short*)(ws + alloc((size_t)HID_*HID_*2));
    unsigned short* Vrt    = (unsigned short*)(ws + alloc((size_t)HID_*DIM_*2));
    unsigned short* Vzt    = (unsigned short*)(ws + alloc((size_t)HID_*DIM_*2));
    unsigned short* Vst    = (unsigned short*)(ws + alloc((size_t)HID_*DIM_*2));
    unsigned short* Wxt    = (unsigned short*)(ws + alloc((size_t)OUT_*HID_*2));
    unsigned short* xbuf_b = (unsigned short*)(ws + alloc((size_t)B_*OUT_*2));
    unsigned short* s_b    = (unsigned short*)(ws + alloc((size_t)B_*HID_*2));
    unsigned short* rs_b   = (unsigned short*)(ws + alloc((size_t)B_*HID_*2));
    float* sb0    = (float*)(ws + alloc((size_t)B_*HID_*4));
    float* sb1    = (float*)(ws + alloc((size_t)B_*HID_*4));
    float* pre    = (float*)(ws + alloc((size_t)B_*K3_*4));
    float* logits = (float*)(ws + alloc((size_t)B_*OUT_*4));
    size_t base_need = off;
    unsigned short* xb16 = (unsigned short*)(ws + alloc((size_t)B_*T_*DIM_*2));
    const int use_xb = (off <= ws_size) ? 1 : 0;
    (void)base_need;

    // ---- prep: weight transposes (+ x conversion) ----
    k_tr<<<dim3(OUT_/32, K3_/32),  256, 0, stream>>>(Wt,   W,  OUT_, K3_, 0);     // W [512][3072]
    k_tr<<<dim3(HID_/32, 2048/32), 256, 0, stream>>>(Urzt, U,  HID_, K3_, 0);     // U[:, :2048]
    k_tr<<<dim3(HID_/32, HID_/32), 256, 0, stream>>>(Ust,  U,  HID_, K3_, 2048);  // U[:, 2048:]
    k_tr<<<dim3(DIM_/32, HID_/32), 256, 0, stream>>>(Vrt,  Vr, DIM_, HID_, 0);    // Vr [512][1024]
    k_tr<<<dim3(DIM_/32, HID_/32), 256, 0, stream>>>(Vzt,  Vz, DIM_, HID_, 0);
    k_tr<<<dim3(DIM_/32, HID_/32), 256, 0, stream>>>(Vst,  Vs, DIM_, HID_, 0);
    k_tr<<<dim3(HID_/32, OUT_/32), 256, 0, stream>>>(Wxt,  Wx, HID_, OUT_, 0);    // Wx [1024][512]
    if (use_xb){
        int n4 = B_*T_*DIM_/4;
        k_cvtx<<<(n4 + 255)/256, 256, 0, stream>>>((const float4*)x, (ushort4*)xb16, n4);
    }
    k_init<<<(B_*HID_ + 255)/256, 256, 0, stream>>>(x0, s0, xbuf_b, sb0, s_b);

    for (int t = 0; t < T_; ++t){
        float* sp = (t & 1) ? sb1 : sb0;
        float* sn = (t & 1) ? sb0 : sb1;
        k_gemmA<<<192, 256, 0, stream>>>(xbuf_b, xb16, x, s_b, sp,
                                         Wt, Vrt, Vzt, Vst, Urzt, b,
                                         pre, rs_b, t, use_xb);
        k_gemmB<<<64, 256, 0, stream>>>(rs_b, Ust, pre, sp, sn, s_b);
        k_gemmC<<<32, 256, 0, stream>>>(s_b, Wxt, bx, logits);
        k_soft <<<128, 256, 0, stream>>>(logits, Wy, by, xbuf_b, out, t);
    }
}